// Round 1
// baseline (10131.361 us; speedup 1.0000x reference)
//
#include <hip/hip_runtime.h>
#include <stdint.h>

#define T_STEPS 2048
#define BATCH   64
#define IN_SZ   256
#define HID     512
#define FANG    768          // HID + IN_SZ
#define NLAYER  2
#define TOT_STEPS (T_STEPS*NLAYER)

// -------------------------------------------------------------------------
// Kernel 1: Xproj[t*B+b][j] = gate_b[j] + sum_k input[t,b,k] * gate_w[j][512+k]
// M = T*B = 131072, N = 512, K = 256.  64x64 tile, 256 threads, 4x4 per thread.
// -------------------------------------------------------------------------
__global__ __launch_bounds__(256) void xproj_kernel(
    const float* __restrict__ input,
    const float* __restrict__ gate_w,
    const float* __restrict__ gate_b,
    float* __restrict__ xproj)
{
    __shared__ float As[64][68];   // pad 68: 16B-aligned rows, conflict-free float4
    __shared__ float Bs[64][68];

    const int bx = blockIdx.x;     // N tile 0..7
    const int by = blockIdx.y;     // M tile 0..2047
    const int tid = threadIdx.x;
    const int tx = tid & 15, ty = tid >> 4;
    const int m0 = by * 64, j0 = bx * 64;

    float acc[4][4] = {};

    for (int kc = 0; kc < 4; ++kc) {
        #pragma unroll
        for (int l = 0; l < 16; ++l) {
            int idx = tid + l * 256;
            int i = idx >> 6, kk = idx & 63;
            As[i][kk] = input[(size_t)(m0 + i) * IN_SZ + kc * 64 + kk];
            Bs[i][kk] = gate_w[(size_t)(j0 + i) * FANG + HID + kc * 64 + kk];
        }
        __syncthreads();
        #pragma unroll
        for (int kk = 0; kk < 64; kk += 4) {
            float4 a[4], b[4];
            #pragma unroll
            for (int i = 0; i < 4; ++i) a[i] = *(const float4*)&As[ty * 4 + i][kk];
            #pragma unroll
            for (int jj = 0; jj < 4; ++jj) b[jj] = *(const float4*)&Bs[tx * 4 + jj][kk];
            #pragma unroll
            for (int i = 0; i < 4; ++i)
                #pragma unroll
                for (int jj = 0; jj < 4; ++jj)
                    acc[i][jj] += a[i].x * b[jj].x + a[i].y * b[jj].y
                                + a[i].z * b[jj].z + a[i].w * b[jj].w;
        }
        __syncthreads();
    }

    #pragma unroll
    for (int i = 0; i < 4; ++i) {
        int m = m0 + ty * 4 + i;
        #pragma unroll
        for (int jj = 0; jj < 4; ++jj) {
            int j = j0 + tx * 4 + jj;
            xproj[(size_t)m * HID + j] = acc[i][jj] + gate_b[j];
        }
    }
}

// -------------------------------------------------------------------------
// Kernel 2: the recurrence. 256 WGs = 64 batch x 4 j-slices, 512 threads.
// blk = s*64 + b  (so a batch-group's 4 WGs share blk%8 -> likely same XCD).
// Thread (r = tid>>2, cc = tid&3) owns Wh[s*128+r][cc*128 .. +128] in VGPRs.
// h exchange: double-buffered global uint64 array, (tag<<32)|float_bits,
// agent-scope relaxed atomics (data and flag are one word -> no fences).
// -------------------------------------------------------------------------
__global__ __launch_bounds__(512) void lstm_kernel(
    const float* __restrict__ gate_w,
    const float* __restrict__ xproj,
    unsigned long long* __restrict__ hexch)
{
    const int blk = blockIdx.x;     // 0..255
    const int s   = blk >> 6;       // j-slice 0..3
    const int b   = blk & 63;       // batch row
    const int tid = threadIdx.x;    // 0..511
    const int r   = tid >> 2;       // 0..127 row within slice
    const int cc  = tid & 3;        // k-chunk 0..3
    const int j   = s * 128 + r;    // global hidden index

    __shared__ float h_lds[4 * 132];   // stride 132: 4 disjoint bank spans for float4 bcast
    __shared__ float x_lds[128];

    // Register-resident Wh chunk (128 fp32 = 128 VGPRs, compile-time indexed)
    float w[128];
    {
        const float* src = gate_w + (size_t)j * FANG + cc * 128;
        #pragma unroll
        for (int i = 0; i < 128; i += 4) {
            float4 v = *(const float4*)(src + i);
            w[i] = v.x; w[i + 1] = v.y; w[i + 2] = v.z; w[i + 3] = v.w;
        }
    }

    float cval = 0.0f;
    const bool owner = (cc == 0);

    for (int step = 0; step < TOT_STEPS; ++step) {
        const int t = step & (T_STEPS - 1);

        // prefetch this WG's Xproj slice (overlaps the poll)
        float xv = 0.0f;
        if (tid < 128)
            xv = xproj[((size_t)t * BATCH + b) * HID + s * 128 + tid];

        // poll h produced at end of step-1 (tag == step) from buffer step%2
        {
            unsigned long long* buf = hexch + (size_t)(step & 1) * (BATCH * HID) + (size_t)b * HID;
            unsigned long long v;
            int spin = 0;
            for (;;) {
                v = __hip_atomic_load(buf + tid, __ATOMIC_RELAXED, __HIP_MEMORY_SCOPE_AGENT);
                if ((unsigned)(v >> 32) == (unsigned)step) break;
                if (++spin > (1 << 22)) break;   // safety bailout (never fires if healthy)
                __builtin_amdgcn_s_sleep(1);
            }
            h_lds[(tid >> 7) * 132 + (tid & 127)] = __uint_as_float((unsigned)v);
        }
        if (tid < 128) x_lds[tid] = xv;
        __syncthreads();

        // partial dot: 128 FMAs against register-resident Wh
        float p = 0.0f;
        const float* hb = &h_lds[cc * 132];
        #pragma unroll
        for (int i = 0; i < 128; i += 4) {
            float4 hv = *(const float4*)(hb + i);
            p += w[i] * hv.x + w[i + 1] * hv.y + w[i + 2] * hv.z + w[i + 3] * hv.w;
        }
        // reduce across the 4 k-chunk lanes
        p += __shfl_xor(p, 1);
        p += __shfl_xor(p, 2);

        if (owner) {
            float g = p + x_lds[r];
            g = fminf(fmaxf(g, -30.0f), 30.0f);        // exact: |tanh|,|sigmoid| saturated
            float sg = 1.0f / (1.0f + __expf(-g));      // sigmoid
            float e2 = __expf(2.0f * g);                // tanh(g)
            float ch = (e2 - 1.0f) / (e2 + 1.0f);
            cval = cval * sg + ch * sg;                 // matches reference form
            float ca = fminf(fmaxf(cval, -15.0f), 15.0f);
            float e3 = __expf(2.0f * ca);               // tanh(c)
            float th = (e3 - 1.0f) / (e3 + 1.0f);
            float hval = th * sg;

            unsigned long long outv =
                ((unsigned long long)(unsigned)(step + 1) << 32)
                | (unsigned long long)__float_as_uint(hval);
            unsigned long long* nbuf =
                hexch + (size_t)((step + 1) & 1) * (BATCH * HID) + (size_t)b * HID;
            __hip_atomic_store(nbuf + j, outv, __ATOMIC_RELAXED, __HIP_MEMORY_SCOPE_AGENT);
        }
        __syncthreads();   // protect h_lds from next-iteration overwrite
    }
}

// -------------------------------------------------------------------------
// Kernel 3: output = h_final @ out_w.T + out_b   (64x256, trivial)
// Final h lives in hexch buffer (TOT_STEPS % 2) == 0 with tag TOT_STEPS.
// -------------------------------------------------------------------------
__global__ __launch_bounds__(256) void out_kernel(
    const unsigned long long* __restrict__ hexch,
    const float* __restrict__ out_w,
    const float* __restrict__ out_b,
    float* __restrict__ out)
{
    const int b  = blockIdx.x;    // 64
    const int jt = threadIdx.x;   // 256
    __shared__ float hrow[512];

    for (int k = jt; k < HID; k += 256)
        hrow[k] = __uint_as_float((unsigned)hexch[(size_t)b * HID + k]);
    __syncthreads();

    float acc = out_b[jt];
    const float* wr = out_w + (size_t)jt * HID;
    #pragma unroll 8
    for (int k = 0; k < HID; ++k)
        acc += hrow[k] * wr[k];
    out[(size_t)b * IN_SZ + jt] = acc;
}

// -------------------------------------------------------------------------
extern "C" void kernel_launch(void* const* d_in, const int* in_sizes, int n_in,
                              void* d_out, int out_size, void* d_ws, size_t ws_size,
                              hipStream_t stream)
{
    const float* input  = (const float*)d_in[0];
    const float* gate_w = (const float*)d_in[1];
    const float* gate_b = (const float*)d_in[2];
    const float* out_w  = (const float*)d_in[3];
    const float* out_b  = (const float*)d_in[4];
    float* out = (float*)d_out;

    // workspace layout: Xproj (256 MB fp32) | hexch double buffer (512 KB)
    float* xproj = (float*)d_ws;
    const size_t xbytes = (size_t)T_STEPS * BATCH * HID * sizeof(float);
    unsigned long long* hexch = (unsigned long long*)((char*)d_ws + xbytes);

    // both exchange buffers must be zeroed every launch (tag 0 == initial h=0,
    // and stale tags from a previous replay must never alias a live tag)
    hipMemsetAsync(hexch, 0, (size_t)2 * BATCH * HID * sizeof(unsigned long long), stream);

    dim3 g1(8, 2048);
    xproj_kernel<<<g1, 256, 0, stream>>>(input, gate_w, gate_b, xproj);
    lstm_kernel<<<256, 512, 0, stream>>>(gate_w, xproj, hexch);
    out_kernel<<<64, 256, 0, stream>>>(hexch, out_w, out_b, out);
}

// Round 2
// 9438.146 us; speedup vs baseline: 1.0734x; 1.0734x over previous
//
#include <hip/hip_runtime.h>
#include <stdint.h>

#define T_STEPS 2048
#define BATCH   64
#define IN_SZ   256
#define HID     512
#define FANG    768          // HID + IN_SZ
#define NLAYER  2
#define TOT_STEPS (T_STEPS*NLAYER)

typedef _Float16 h2 __attribute__((ext_vector_type(2)));

__device__ __forceinline__ float dot2f(h2 a, h2 b, float c) {
#if __has_builtin(__builtin_amdgcn_fdot2)
    return __builtin_amdgcn_fdot2(a, b, c, false);
#else
    return c + (float)a.x * (float)b.x + (float)a.y * (float)b.y;
#endif
}

// -------------------------------------------------------------------------
// Kernel 1: Xproj[t*B+b][j] = gate_b[j] + sum_k input[t,b,k] * gate_w[j][512+k]
// M = T*B = 131072, N = 512, K = 256.  64x64 tile, 256 threads, 4x4 per thread.
// Round-2 fix: kk-quad rotation by tx on BOTH A and B LDS reads to kill the
// 8-way bank conflicts (row stride 68 floats => lanes tx,tx+2,... collided).
// -------------------------------------------------------------------------
__global__ __launch_bounds__(256) void xproj_kernel(
    const float* __restrict__ input,
    const float* __restrict__ gate_w,
    const float* __restrict__ gate_b,
    float* __restrict__ xproj)
{
    __shared__ float As[64][68];
    __shared__ float Bs[64][68];

    const int bx = blockIdx.x;     // N tile 0..7
    const int by = blockIdx.y;     // M tile 0..2047
    const int tid = threadIdx.x;
    const int tx = tid & 15, ty = tid >> 4;
    const int m0 = by * 64, j0 = bx * 64;

    float acc[4][4] = {};

    for (int kc = 0; kc < 4; ++kc) {
        #pragma unroll
        for (int l = 0; l < 16; ++l) {
            int idx = tid + l * 256;
            int i = idx >> 6, kk = idx & 63;
            As[i][kk] = input[(size_t)(m0 + i) * IN_SZ + kc * 64 + kk];
            Bs[i][kk] = gate_w[(size_t)(j0 + i) * FANG + HID + kc * 64 + kk];
        }
        __syncthreads();
        #pragma unroll
        for (int qq = 0; qq < 16; ++qq) {
            const int kk = ((qq + tx) & 15) * 4;   // rotated quad: bank-conflict-free
            float4 a[4], b[4];
            #pragma unroll
            for (int i = 0; i < 4; ++i) a[i] = *(const float4*)&As[ty * 4 + i][kk];
            #pragma unroll
            for (int jj = 0; jj < 4; ++jj) b[jj] = *(const float4*)&Bs[tx * 4 + jj][kk];
            #pragma unroll
            for (int i = 0; i < 4; ++i)
                #pragma unroll
                for (int jj = 0; jj < 4; ++jj)
                    acc[i][jj] += a[i].x * b[jj].x + a[i].y * b[jj].y
                                + a[i].z * b[jj].z + a[i].w * b[jj].w;
        }
        __syncthreads();
    }

    #pragma unroll
    for (int i = 0; i < 4; ++i) {
        int m = m0 + ty * 4 + i;
        #pragma unroll
        for (int jj = 0; jj < 4; ++jj) {
            int j = j0 + tx * 4 + jj;
            xproj[(size_t)m * HID + j] = acc[i][jj] + gate_b[j];
        }
    }
}

// -------------------------------------------------------------------------
// Kernel 2: the recurrence. 256 WGs = 64 batch x 4 j-slices, 512 threads.
// Thread (r = tid>>2, cc = tid&3) owns Wh[s*128+r][cc*128 .. +128] as 64
// packed v2f16 registers; dot via v_dot2_f32_f16 (fp32 accumulate).
// h exchange: double-buffered global uint64 (tag<<32)|h_bits, agent-scope
// relaxed atomics (data and flag one word -> no fences). Single barrier per
// step via double-buffered h_lds/x_lds.
// -------------------------------------------------------------------------
__global__ __launch_bounds__(512, 2) void lstm_kernel(
    const float* __restrict__ gate_w,
    const float* __restrict__ xproj,
    unsigned long long* __restrict__ hexch)
{
    const int blk = blockIdx.x;     // 0..255
    const int s   = blk >> 6;       // j-slice 0..3
    const int b   = blk & 63;       // batch row
    const int tid = threadIdx.x;    // 0..511
    const int r   = tid >> 2;       // 0..127 row within slice
    const int cc  = tid & 3;        // k-chunk 0..3
    const int j   = s * 128 + r;    // global hidden index

    // h as fp16, chunk stride 136 halves (272 B): cc-chunks on disjoint banks,
    // 16-B aligned for b128 reads. Double-buffered for single-barrier steps.
    __shared__ _Float16 h_lds[2][4][136];
    __shared__ float    x_lds[2][128];

    // Register-resident Wh chunk: 128 fp32 -> 64 packed v2f16 (64 VGPRs)
    h2 w2[64];
    {
        const float4* src = (const float4*)(gate_w + (size_t)j * FANG + cc * 128);
        #pragma unroll
        for (int i = 0; i < 32; ++i) {
            float4 v = src[i];
            w2[2 * i]     = h2{(_Float16)v.x, (_Float16)v.y};
            w2[2 * i + 1] = h2{(_Float16)v.z, (_Float16)v.w};
        }
    }

    float cval = 0.0f;
    const bool owner = (cc == 0);

    for (int step = 0; step < TOT_STEPS; ++step) {
        const int t   = step & (T_STEPS - 1);
        const int buf = step & 1;

        // prefetch this WG's Xproj slice (in flight during the poll)
        float xv = 0.0f;
        if (tid < 128)
            xv = xproj[((size_t)t * BATCH + b) * HID + s * 128 + tid];

        // poll h produced at end of step-1 (tag == step) from buffer step%2
        {
            unsigned long long* pbuf = hexch + (size_t)buf * (BATCH * HID) + (size_t)b * HID;
            unsigned long long v;
            int spin = 0;
            for (;;) {
                v = __hip_atomic_load(pbuf + tid, __ATOMIC_RELAXED, __HIP_MEMORY_SCOPE_AGENT);
                if ((unsigned)(v >> 32) == (unsigned)step) break;
                ++spin;
                if (spin > (1 << 20)) break;          // safety bailout
                if (spin > 8) __builtin_amdgcn_s_sleep(1);
            }
            h_lds[buf][tid >> 7][tid & 127] = (_Float16)__uint_as_float((unsigned)v);
        }
        if (tid < 128) x_lds[buf][tid] = xv;
        __syncthreads();   // the only barrier per step

        // partial dot: 64 x v_dot2_f32_f16 against register-resident Wh
        const float4* hb = (const float4*)&h_lds[buf][cc][0];
        float p0 = 0.f, p1 = 0.f, p2 = 0.f, p3 = 0.f;
        #pragma unroll
        for (int i = 0; i < 16; ++i) {
            float4 rv = hb[i];                         // ds_read_b128, conflict-free
            p0 = dot2f(w2[4 * i + 0], __builtin_bit_cast(h2, rv.x), p0);
            p1 = dot2f(w2[4 * i + 1], __builtin_bit_cast(h2, rv.y), p1);
            p2 = dot2f(w2[4 * i + 2], __builtin_bit_cast(h2, rv.z), p2);
            p3 = dot2f(w2[4 * i + 3], __builtin_bit_cast(h2, rv.w), p3);
        }
        float p = (p0 + p1) + (p2 + p3);

        // reduce across the 4 k-chunk lanes
        p += __shfl_xor(p, 1);
        p += __shfl_xor(p, 2);

        if (owner) {
            float g = p + x_lds[buf][r];
            g = fminf(fmaxf(g, -30.0f), 30.0f);
            float sg = 1.0f / (1.0f + __expf(-g));      // sigmoid
            float e2 = __expf(2.0f * g);                // tanh(g)
            float ch = (e2 - 1.0f) / (e2 + 1.0f);
            cval = cval * sg + ch * sg;
            float ca = fminf(fmaxf(cval, -15.0f), 15.0f);
            float e3 = __expf(2.0f * ca);               // tanh(c)
            float th = (e3 - 1.0f) / (e3 + 1.0f);
            float hval = th * sg;

            unsigned long long outv =
                ((unsigned long long)(unsigned)(step + 1) << 32)
                | (unsigned long long)__float_as_uint(hval);
            unsigned long long* nbuf =
                hexch + (size_t)((step + 1) & 1) * (BATCH * HID) + (size_t)b * HID;
            __hip_atomic_store(nbuf + j, outv, __ATOMIC_RELAXED, __HIP_MEMORY_SCOPE_AGENT);
        }
        // no trailing barrier: next step writes the other LDS buffer,
        // and the next __syncthreads() bounds intra-WG skew to one step.
    }
}

// -------------------------------------------------------------------------
// Kernel 3: output = h_final @ out_w.T + out_b   (64x256, trivial)
// Final h lives in hexch buffer (TOT_STEPS % 2) == 0 with tag TOT_STEPS.
// -------------------------------------------------------------------------
__global__ __launch_bounds__(256) void out_kernel(
    const unsigned long long* __restrict__ hexch,
    const float* __restrict__ out_w,
    const float* __restrict__ out_b,
    float* __restrict__ out)
{
    const int b  = blockIdx.x;    // 64
    const int jt = threadIdx.x;   // 256
    __shared__ float hrow[512];

    for (int k = jt; k < HID; k += 256)
        hrow[k] = __uint_as_float((unsigned)hexch[(size_t)b * HID + k]);
    __syncthreads();

    float acc = out_b[jt];
    const float* wr = out_w + (size_t)jt * HID;
    #pragma unroll 8
    for (int k = 0; k < HID; ++k)
        acc += hrow[k] * wr[k];
    out[(size_t)b * IN_SZ + jt] = acc;
}

// -------------------------------------------------------------------------
extern "C" void kernel_launch(void* const* d_in, const int* in_sizes, int n_in,
                              void* d_out, int out_size, void* d_ws, size_t ws_size,
                              hipStream_t stream)
{
    const float* input  = (const float*)d_in[0];
    const float* gate_w = (const float*)d_in[1];
    const float* gate_b = (const float*)d_in[2];
    const float* out_w  = (const float*)d_in[3];
    const float* out_b  = (const float*)d_in[4];
    float* out = (float*)d_out;

    // workspace layout: Xproj (256 MB fp32) | hexch double buffer (512 KB)
    float* xproj = (float*)d_ws;
    const size_t xbytes = (size_t)T_STEPS * BATCH * HID * sizeof(float);
    unsigned long long* hexch = (unsigned long long*)((char*)d_ws + xbytes);

    // zero both exchange buffers every launch (tag 0 == initial h=0; stale
    // tags from a previous replay must never alias a live tag)
    hipMemsetAsync(hexch, 0, (size_t)2 * BATCH * HID * sizeof(unsigned long long), stream);

    dim3 g1(8, 2048);
    xproj_kernel<<<g1, 256, 0, stream>>>(input, gate_w, gate_b, xproj);
    lstm_kernel<<<256, 512, 0, stream>>>(gate_w, xproj, hexch);
    out_kernel<<<64, 256, 0, stream>>>(hexch, out_w, out_b, out);
}

// Round 3
// 8091.520 us; speedup vs baseline: 1.2521x; 1.1664x over previous
//
#include <hip/hip_runtime.h>
#include <stdint.h>

#define T_STEPS 2048
#define BATCH   64
#define IN_SZ   256
#define HID     512
#define FANG    768          // HID + IN_SZ
#define NLAYER  2
#define TOT_STEPS (T_STEPS*NLAYER)

typedef _Float16 h2 __attribute__((ext_vector_type(2)));
typedef unsigned long long u64;
typedef unsigned int u32;

__device__ __forceinline__ float dot2f(h2 a, h2 b, float c) {
#if __has_builtin(__builtin_amdgcn_fdot2)
    return __builtin_amdgcn_fdot2(a, b, c, false);
#else
    return c + (float)a.x * (float)b.x + (float)a.y * (float)b.y;
#endif
}

// -------------------------------------------------------------------------
// Kernel 1: Xproj[m][j] = gate_b[j] + sum_k input[m,k] * gate_wx[j][k]
// Persistent-B: 512 WGs = 8 j-tiles x 64 m-groups. B (64j x 256k, fp16)
// stays LDS-resident for the WG's whole life; 32 m-tiles of 64 rows stream
// through As. Inner loop: v_dot2_f32_f16, fp32 accumulate.
// -------------------------------------------------------------------------
__global__ __launch_bounds__(256) void xproj_kernel(
    const float* __restrict__ input,
    const float* __restrict__ gate_w,
    const float* __restrict__ gate_b,
    float* __restrict__ xproj)
{
    __shared__ _Float16 Bs[64][264];   // 264-half row pad (528 B)
    __shared__ _Float16 As[64][264];

    const int jt = blockIdx.x;         // 0..7
    const int mg = blockIdx.y;         // 0..63
    const int tid = threadIdx.x;
    const int tx = tid & 15, ty = tid >> 4;
    const int j0 = jt * 64;

    // stage B once (fp32 -> fp16)
    #pragma unroll
    for (int l = 0; l < 16; ++l) {
        int e = tid + l * 256;
        int i = e >> 6, kq = e & 63;
        float4 v = *(const float4*)&gate_w[(size_t)(j0 + i) * FANG + HID + kq * 4];
        *(h2*)&Bs[i][kq * 4]     = h2{(_Float16)v.x, (_Float16)v.y};
        *(h2*)&Bs[i][kq * 4 + 2] = h2{(_Float16)v.z, (_Float16)v.w};
    }

    const float4 gb = *(const float4*)&gate_b[j0 + tx * 4];

    for (int mt = 0; mt < 32; ++mt) {
        const int m0 = (mg * 32 + mt) * 64;
        __syncthreads();   // As free again (and publishes Bs on first iter)
        #pragma unroll
        for (int l = 0; l < 16; ++l) {
            int e = tid + l * 256;
            int i = e >> 6, kq = e & 63;
            float4 v = *(const float4*)&input[(size_t)(m0 + i) * IN_SZ + kq * 4];
            *(h2*)&As[i][kq * 4]     = h2{(_Float16)v.x, (_Float16)v.y};
            *(h2*)&As[i][kq * 4 + 2] = h2{(_Float16)v.z, (_Float16)v.w};
        }
        __syncthreads();

        float acc[4][4] = {};
        #pragma unroll
        for (int q = 0; q < 32; ++q) {
            const int k = ((q + tx) & 31) * 8;   // rotated: spreads banks
            float4 av[4], bv[4];
            #pragma unroll
            for (int i = 0; i < 4; ++i)  av[i] = *(const float4*)&As[ty * 4 + i][k];
            #pragma unroll
            for (int jj = 0; jj < 4; ++jj) bv[jj] = *(const float4*)&Bs[tx * 4 + jj][k];
            #pragma unroll
            for (int i = 0; i < 4; ++i) {
                h2 a0 = __builtin_bit_cast(h2, av[i].x);
                h2 a1 = __builtin_bit_cast(h2, av[i].y);
                h2 a2 = __builtin_bit_cast(h2, av[i].z);
                h2 a3 = __builtin_bit_cast(h2, av[i].w);
                #pragma unroll
                for (int jj = 0; jj < 4; ++jj) {
                    acc[i][jj] = dot2f(a0, __builtin_bit_cast(h2, bv[jj].x), acc[i][jj]);
                    acc[i][jj] = dot2f(a1, __builtin_bit_cast(h2, bv[jj].y), acc[i][jj]);
                    acc[i][jj] = dot2f(a2, __builtin_bit_cast(h2, bv[jj].z), acc[i][jj]);
                    acc[i][jj] = dot2f(a3, __builtin_bit_cast(h2, bv[jj].w), acc[i][jj]);
                }
            }
        }

        #pragma unroll
        for (int i = 0; i < 4; ++i) {
            float4 o = {acc[i][0] + gb.x, acc[i][1] + gb.y,
                        acc[i][2] + gb.z, acc[i][3] + gb.w};
            *(float4*)&xproj[(size_t)(m0 + ty * 4 + i) * HID + j0 + tx * 4] = o;
        }
    }
}

// -------------------------------------------------------------------------
// Kernel 2: the recurrence. 256 WGs = 4 j-slices x 64 batch, 512 threads.
// Exchange v3: producers pack 4 fp16 h per 8B word (32 words/WG, relaxed
// agent stores), __syncthreads drains vmcnt, then ONE flag store per WG.
// Consumers: 4 threads poll the 4 global flags, relay via LDS `ready`;
// 128 loader threads spin on LDS (no fabric traffic), then one-shot bulk
// load of 128 words. Back-pressure: every WG consumes every WG's flag, so
// buffer[step&1] can't be overwritten before all its readers are done.
// -------------------------------------------------------------------------
__global__ __launch_bounds__(512, 2) void lstm_kernel(
    const float* __restrict__ gate_w,
    const float* __restrict__ xproj,
    u64* __restrict__ hdata,          // [2][BATCH][128] packed 4xfp16
    u32* __restrict__ hflag)          // [2][BATCH][16]  (64B row stride)
{
    const int blk = blockIdx.x;     // 0..255
    const int s   = blk >> 6;       // j-slice 0..3
    const int b   = blk & 63;       // batch row
    const int tid = threadIdx.x;    // 0..511
    const int r   = tid >> 2;       // 0..127 row within slice
    const int cc  = tid & 3;        // k-chunk 0..3
    const int j   = s * 128 + r;
    const int lane = tid & 63;

    __shared__ _Float16 h_lds[2][4][136];
    __shared__ float    x_lds[2][128];
    __shared__ int      ready[2][4];

    // Register-resident Wh chunk: 128 fp32 -> 64 packed v2f16
    h2 w2[64];
    {
        const float4* src = (const float4*)(gate_w + (size_t)j * FANG + cc * 128);
        #pragma unroll
        for (int i = 0; i < 32; ++i) {
            float4 v = src[i];
            w2[2 * i]     = h2{(_Float16)v.x, (_Float16)v.y};
            w2[2 * i + 1] = h2{(_Float16)v.z, (_Float16)v.w};
        }
    }

    if (tid < 8) ready[tid >> 2][tid & 3] = 0;
    __syncthreads();

    float cval = 0.0f;
    const bool owner = (cc == 0);

    for (int step = 0; step < TOT_STEPS; ++step) {
        const int t   = step & (T_STEPS - 1);
        const int buf = step & 1;

        // xproj prefetch (in flight during the poll)
        float xv = 0.0f;
        if (tid < 128)
            xv = xproj[((size_t)t * BATCH + b) * HID + s * 128 + tid];

        if (step == 0) {
            if (tid < 128) {
                ushort4 z = {0, 0, 0, 0};
                *(ushort4*)&h_lds[0][tid >> 5][(tid & 31) * 4] = z;
            }
        } else {
            if (tid < 4) {
                const u32* fp = hflag + ((size_t)buf * BATCH + b) * 16 + tid;
                int spin = 0;
                while (__hip_atomic_load(fp, __ATOMIC_RELAXED, __HIP_MEMORY_SCOPE_AGENT)
                       != (u32)step) {
                    if (++spin > (1 << 20)) break;   // safety bailout
                    if (spin > 32) __builtin_amdgcn_s_sleep(1);
                }
                __hip_atomic_store(&ready[buf][tid], step,
                                   __ATOMIC_RELAXED, __HIP_MEMORY_SCOPE_WORKGROUP);
            }
            if (tid < 128) {
                int spin = 0;
                while (__hip_atomic_load(&ready[buf][tid >> 5],
                                         __ATOMIC_RELAXED, __HIP_MEMORY_SCOPE_WORKGROUP)
                       != step) {
                    if (++spin > (1 << 22)) break;
                }
                u64 v = __hip_atomic_load(hdata + ((size_t)buf * BATCH + b) * 128 + tid,
                                          __ATOMIC_RELAXED, __HIP_MEMORY_SCOPE_AGENT);
                ushort4 u = { (unsigned short)v,         (unsigned short)(v >> 16),
                              (unsigned short)(v >> 32), (unsigned short)(v >> 48) };
                *(ushort4*)&h_lds[buf][tid >> 5][(tid & 31) * 4] = u;
            }
        }
        if (tid < 128) x_lds[buf][tid] = xv;
        __syncthreads();   // h_lds/x_lds ready

        // 64 x v_dot2_f32_f16 against register-resident Wh
        const float4* hb = (const float4*)&h_lds[buf][cc][0];
        float p0 = 0.f, p1 = 0.f, p2 = 0.f, p3 = 0.f;
        #pragma unroll
        for (int i = 0; i < 16; ++i) {
            float4 rv = hb[i];
            p0 = dot2f(w2[4 * i + 0], __builtin_bit_cast(h2, rv.x), p0);
            p1 = dot2f(w2[4 * i + 1], __builtin_bit_cast(h2, rv.y), p1);
            p2 = dot2f(w2[4 * i + 2], __builtin_bit_cast(h2, rv.z), p2);
            p3 = dot2f(w2[4 * i + 3], __builtin_bit_cast(h2, rv.w), p3);
        }
        float p = (p0 + p1) + (p2 + p3);
        p += __shfl_xor(p, 1);
        p += __shfl_xor(p, 2);

        int hi = 0;
        if (owner) {
            float g = p + x_lds[buf][r];
            g = fminf(fmaxf(g, -30.0f), 30.0f);
            float sg = 1.0f / (1.0f + __expf(-g));      // sigmoid
            float e2 = __expf(2.0f * g);                // tanh(g)
            float ch = (e2 - 1.0f) / (e2 + 1.0f);
            cval = cval * sg + ch * sg;
            float ca = fminf(fmaxf(cval, -15.0f), 15.0f);
            float e3 = __expf(2.0f * ca);               // tanh(c)
            float th = (e3 - 1.0f) / (e3 + 1.0f);
            float hval = th * sg;
            hi = (int)__builtin_bit_cast(unsigned short, (_Float16)hval);
        }
        // pack 4 owner fp16 (lanes b0,b0+4,b0+8,b0+12) into one 8B word
        const int b0 = lane & 48;
        int x0 = __shfl(hi, b0);
        int x1 = __shfl(hi, b0 + 4);
        int x2 = __shfl(hi, b0 + 8);
        int x3 = __shfl(hi, b0 + 12);
        if ((tid & 15) == 0) {
            u64 word = (u64)(unsigned short)x0
                     | ((u64)(unsigned short)x1 << 16)
                     | ((u64)(unsigned short)x2 << 32)
                     | ((u64)(unsigned short)x3 << 48);
            __hip_atomic_store(hdata + ((size_t)((step + 1) & 1) * BATCH + b) * 128
                                     + s * 32 + (tid >> 4),
                               word, __ATOMIC_RELAXED, __HIP_MEMORY_SCOPE_AGENT);
        }
        __syncthreads();   // drains vmcnt(0) per wave -> data at LLC before flag
        if (tid == 0)
            __hip_atomic_store(hflag + ((size_t)((step + 1) & 1) * BATCH + b) * 16 + s,
                               (u32)(step + 1),
                               __ATOMIC_RELAXED, __HIP_MEMORY_SCOPE_AGENT);
    }
}

// -------------------------------------------------------------------------
// Kernel 3: output = h_final @ out_w.T + out_b. Final h is in hdata buf 0
// (TOT_STEPS even), packed 4xfp16 per word. Kernel boundary = full fence.
// -------------------------------------------------------------------------
__global__ __launch_bounds__(256) void out_kernel(
    const u64* __restrict__ hdata,
    const float* __restrict__ out_w,
    const float* __restrict__ out_b,
    float* __restrict__ out)
{
    const int b  = blockIdx.x;    // 64
    const int jt = threadIdx.x;   // 256
    __shared__ float hrow[512];

    if (jt < 128) {
        u64 v = hdata[(size_t)b * 128 + jt];
        hrow[4 * jt + 0] = (float)__builtin_bit_cast(_Float16, (unsigned short)v);
        hrow[4 * jt + 1] = (float)__builtin_bit_cast(_Float16, (unsigned short)(v >> 16));
        hrow[4 * jt + 2] = (float)__builtin_bit_cast(_Float16, (unsigned short)(v >> 32));
        hrow[4 * jt + 3] = (float)__builtin_bit_cast(_Float16, (unsigned short)(v >> 48));
    }
    __syncthreads();

    float acc = out_b[jt];
    const float* wr = out_w + (size_t)jt * HID;
    #pragma unroll 8
    for (int k = 0; k < HID; ++k)
        acc += hrow[k] * wr[k];
    out[(size_t)b * IN_SZ + jt] = acc;
}

// -------------------------------------------------------------------------
extern "C" void kernel_launch(void* const* d_in, const int* in_sizes, int n_in,
                              void* d_out, int out_size, void* d_ws, size_t ws_size,
                              hipStream_t stream)
{
    const float* input  = (const float*)d_in[0];
    const float* gate_w = (const float*)d_in[1];
    const float* gate_b = (const float*)d_in[2];
    const float* out_w  = (const float*)d_in[3];
    const float* out_b  = (const float*)d_in[4];
    float* out = (float*)d_out;

    // ws layout: Xproj fp32 (256 MB) | hdata (128 KB) | hflag (8 KB)
    float* xproj = (float*)d_ws;
    const size_t xbytes = (size_t)T_STEPS * BATCH * HID * sizeof(float);
    u64* hdata = (u64*)((char*)d_ws + xbytes);
    u32* hflag = (u32*)((char*)d_ws + xbytes + (size_t)2 * BATCH * 128 * sizeof(u64));

    // flags must be zeroed every launch: a graph replay would otherwise see
    // stale tag 4095 at step 4095 and read stale data
    hipMemsetAsync(hflag, 0, (size_t)2 * BATCH * 16 * sizeof(u32), stream);

    dim3 g1(8, 64);
    xproj_kernel<<<g1, 256, 0, stream>>>(input, gate_w, gate_b, xproj);
    lstm_kernel<<<256, 512, 0, stream>>>(gate_w, xproj, hdata, hflag);
    out_kernel<<<64, 256, 0, stream>>>(hdata, out_w, out_b, out);
}

// Round 6
// 6346.630 us; speedup vs baseline: 1.5963x; 1.2749x over previous
//
#include <hip/hip_runtime.h>
#include <stdint.h>

#define T_STEPS 2048
#define BATCH   64
#define IN_SZ   256
#define HID     512
#define FANG    768          // HID + IN_SZ
#define NLAYER  2
#define TOT_STEPS (T_STEPS*NLAYER)

typedef _Float16 h2 __attribute__((ext_vector_type(2)));
typedef unsigned long long u64;
typedef unsigned int u32;

__device__ __forceinline__ float dot2f(h2 a, h2 b, float c) {
#if __has_builtin(__builtin_amdgcn_fdot2)
    return __builtin_amdgcn_fdot2(a, b, c, false);
#else
    return c + (float)a.x * (float)b.x + (float)a.y * (float)b.y;
#endif
}

// Round-2-PROVEN exchange primitives: device-scope relaxed atomics on a
// single u64 (tag32 | 2xfp16). Tag and data in ONE word -> no fences.
__device__ __forceinline__ u64 ld_llc(const u64* p) {
    return __hip_atomic_load(p, __ATOMIC_RELAXED, __HIP_MEMORY_SCOPE_AGENT);
}
__device__ __forceinline__ void st_llc(u64* p, u64 v) {
    __hip_atomic_store(p, v, __ATOMIC_RELAXED, __HIP_MEMORY_SCOPE_AGENT);
}

// DPP sum helper: x + permuted(x). CTRL must be a compile-time constant:
// 0xB1=quad xor1, 0x4E=quad xor2, 0x124=row_ror:4, 0x128=row_ror:8.
// Together = full 16-lane reduce (pure VALU, no LDS).
template<int CTRL>
__device__ __forceinline__ float dpp_add(float x) {
    int xi = __builtin_bit_cast(int, x);
    int yi = __builtin_amdgcn_update_dpp(0, xi, CTRL, 0xf, 0xf, true);
    return x + __builtin_bit_cast(float, yi);
}
__device__ __forceinline__ float reduce16(float x) {
    x = dpp_add<0xB1>(x);
    x = dpp_add<0x4E>(x);
    x = dpp_add<0x124>(x);
    x = dpp_add<0x128>(x);
    return x;
}

// -------------------------------------------------------------------------
// Kernel 1: Xproj — persistent-B fp16 dot2 GEMM (proven ~450us). Unchanged.
// -------------------------------------------------------------------------
__global__ __launch_bounds__(256) void xproj_kernel(
    const float* __restrict__ input,
    const float* __restrict__ gate_w,
    const float* __restrict__ gate_b,
    float* __restrict__ xproj)
{
    __shared__ _Float16 Bs[64][264];
    __shared__ _Float16 As[64][264];

    const int jt = blockIdx.x;         // 0..7
    const int mg = blockIdx.y;         // 0..63
    const int tid = threadIdx.x;
    const int tx = tid & 15, ty = tid >> 4;
    const int j0 = jt * 64;

    #pragma unroll
    for (int l = 0; l < 16; ++l) {
        int e = tid + l * 256;
        int i = e >> 6, kq = e & 63;
        float4 v = *(const float4*)&gate_w[(size_t)(j0 + i) * FANG + HID + kq * 4];
        *(h2*)&Bs[i][kq * 4]     = h2{(_Float16)v.x, (_Float16)v.y};
        *(h2*)&Bs[i][kq * 4 + 2] = h2{(_Float16)v.z, (_Float16)v.w};
    }

    const float4 gb = *(const float4*)&gate_b[j0 + tx * 4];

    for (int mt = 0; mt < 32; ++mt) {
        const int m0 = (mg * 32 + mt) * 64;
        __syncthreads();
        #pragma unroll
        for (int l = 0; l < 16; ++l) {
            int e = tid + l * 256;
            int i = e >> 6, kq = e & 63;
            float4 v = *(const float4*)&input[(size_t)(m0 + i) * IN_SZ + kq * 4];
            *(h2*)&As[i][kq * 4]     = h2{(_Float16)v.x, (_Float16)v.y};
            *(h2*)&As[i][kq * 4 + 2] = h2{(_Float16)v.z, (_Float16)v.w};
        }
        __syncthreads();

        float acc[4][4] = {};
        #pragma unroll
        for (int q = 0; q < 32; ++q) {
            const int k = ((q + tx) & 31) * 8;
            float4 av[4], bv[4];
            #pragma unroll
            for (int i = 0; i < 4; ++i)  av[i] = *(const float4*)&As[ty * 4 + i][k];
            #pragma unroll
            for (int jj = 0; jj < 4; ++jj) bv[jj] = *(const float4*)&Bs[tx * 4 + jj][k];
            #pragma unroll
            for (int i = 0; i < 4; ++i) {
                h2 a0 = __builtin_bit_cast(h2, av[i].x);
                h2 a1 = __builtin_bit_cast(h2, av[i].y);
                h2 a2 = __builtin_bit_cast(h2, av[i].z);
                h2 a3 = __builtin_bit_cast(h2, av[i].w);
                #pragma unroll
                for (int jj = 0; jj < 4; ++jj) {
                    acc[i][jj] = dot2f(a0, __builtin_bit_cast(h2, bv[jj].x), acc[i][jj]);
                    acc[i][jj] = dot2f(a1, __builtin_bit_cast(h2, bv[jj].y), acc[i][jj]);
                    acc[i][jj] = dot2f(a2, __builtin_bit_cast(h2, bv[jj].z), acc[i][jj]);
                    acc[i][jj] = dot2f(a3, __builtin_bit_cast(h2, bv[jj].w), acc[i][jj]);
                }
            }
        }

        #pragma unroll
        for (int i = 0; i < 4; ++i) {
            float4 o = {acc[i][0] + gb.x, acc[i][1] + gb.y,
                        acc[i][2] + gb.z, acc[i][3] + gb.w};
            *(float4*)&xproj[(size_t)(m0 + ty * 4 + i) * HID + j0 + tx * 4] = o;
        }
    }
}

// -------------------------------------------------------------------------
// Kernel 2: recurrence. 256 WGs = 4 slices x 64 batch, 512 threads.
// Thread (g = tid>>4, c = tid&15) owns rows j0 = s*128+g*4 .. +4, k-chunk
// [c*32, c*32+32): 4x16 = 64 packed v2f16 weights. Each h2 operand feeds
// 4 dot2 -> LDS traffic 32KB/CU/step (4x less than round 2).
// h exchange: hx[2][64][256] u64 words (tag32|2xfp16), relaxed agent
// atomics (round-2-proven). Only 192 REMOTE words polled; own slice goes
// straight to LDS at produce time. LDS double-buffered; ONE barrier/step.
// Stride-20-dword LDS chunks: the 16 chunk bases cover all 32 banks once.
// -------------------------------------------------------------------------
__global__ __launch_bounds__(512, 2) void lstm_kernel(
    const float* __restrict__ gate_w,
    const float* __restrict__ xproj,
    u64* __restrict__ hx)
{
    const int blk = blockIdx.x;     // 0..255
    const int s   = blk >> 6;       // slice 0..3
    const int b   = blk & 63;       // batch row
    const int tid = threadIdx.x;    // 0..511
    const int g   = tid >> 4;       // row group 0..31
    const int c   = tid & 15;       // k-chunk 0..15
    const int j0  = s * 128 + g * 4;

    // [buf][16 chunks * 20 dwords]: logical word w at (w>>4)*20 + (w&15)
    __shared__ u32 h_lds[2][320];

    // weights: w2[rr*16 + kk] = W[j0+rr][c*32 + 2kk .. +1] as v2f16
    h2 w2[64];
    #pragma unroll
    for (int rr = 0; rr < 4; ++rr) {
        const float* wr = gate_w + (size_t)(j0 + rr) * FANG + c * 32;
        #pragma unroll
        for (int kb = 0; kb < 8; ++kb) {
            float4 v = *(const float4*)(wr + kb * 4);
            w2[rr * 16 + kb * 2]     = h2{(_Float16)v.x, (_Float16)v.y};
            w2[rr * 16 + kb * 2 + 1] = h2{(_Float16)v.z, (_Float16)v.w};
        }
    }

    // zero h buffer 0 (step 0 consumes h=0; memset'd hx words also decode to 0)
    if (tid < 256) h_lds[0][(tid >> 4) * 20 + (tid & 15)] = 0;

    float cv0 = 0.0f;   // cell state for this owner lane's row (c<4 only)

    for (int st = 0; st < TOT_STEPS; ++st) {
        const int t   = st & (T_STEPS - 1);
        const int buf = st & 1;

        // owner lanes prefetch their xproj element (overlaps the poll)
        float xv = 0.0f;
        if (c < 4)
            xv = xproj[((size_t)t * BATCH + b) * HID + s * 128 + g * 4 + c];

        // poll the 192 remote words (3 slices); own slice was written to LDS
        if (tid < 192) {
            const int si = tid >> 6;
            const int q  = si + (si >= s);          // skip own slice
            const int w  = q * 64 + (tid & 63);
            const u64* p = hx + ((size_t)buf * BATCH + b) * 256 + w;
            u64 v;
            int spin = 0;
            for (;;) {
                v = ld_llc(p);
                if ((u32)(v >> 32) == (u32)st) break;
                if (++spin > (1 << 16)) break;       // safety bailout
                if (spin > 32) __builtin_amdgcn_s_sleep(1);
            }
            h_lds[buf][(w >> 4) * 20 + (w & 15)] = (u32)v;
        }
        __syncthreads();   // the only barrier per step

        // 64 dot2: 4 rows x 16 h2 words, each operand word feeds 4 dot2
        const u32* hb = &h_lds[buf][c * 20];
        float a0 = 0.f, a1 = 0.f, a2 = 0.f, a3 = 0.f;
        #pragma unroll
        for (int q = 0; q < 4; ++q) {
            float4 rv = *(const float4*)(hb + q * 4);   // conflict-free b128
            h2 x0 = __builtin_bit_cast(h2, rv.x);
            h2 x1 = __builtin_bit_cast(h2, rv.y);
            h2 x2 = __builtin_bit_cast(h2, rv.z);
            h2 x3 = __builtin_bit_cast(h2, rv.w);
            a0 = dot2f(w2[q*4+0], x0, a0); a0 = dot2f(w2[q*4+1], x1, a0);
            a0 = dot2f(w2[q*4+2], x2, a0); a0 = dot2f(w2[q*4+3], x3, a0);
            a1 = dot2f(w2[16+q*4+0], x0, a1); a1 = dot2f(w2[16+q*4+1], x1, a1);
            a1 = dot2f(w2[16+q*4+2], x2, a1); a1 = dot2f(w2[16+q*4+3], x3, a1);
            a2 = dot2f(w2[32+q*4+0], x0, a2); a2 = dot2f(w2[32+q*4+1], x1, a2);
            a2 = dot2f(w2[32+q*4+2], x2, a2); a2 = dot2f(w2[32+q*4+3], x3, a2);
            a3 = dot2f(w2[48+q*4+0], x0, a3); a3 = dot2f(w2[48+q*4+1], x1, a3);
            a3 = dot2f(w2[48+q*4+2], x2, a3); a3 = dot2f(w2[48+q*4+3], x3, a3);
        }

        // 16-lane reduce, pure VALU (DPP): quad xor1, xor2, then ror4, ror8
        a0 = reduce16(a0);
        a1 = reduce16(a1);
        a2 = reduce16(a2);
        a3 = reduce16(a3);

        int hi = 0;
        if (c < 4) {
            float p = (c == 0) ? a0 : (c == 1) ? a1 : (c == 2) ? a2 : a3;
            float gg = p + xv;
            gg = fminf(fmaxf(gg, -30.0f), 30.0f);
            float sg = 1.0f / (1.0f + __expf(-gg));     // sigmoid
            float e2 = __expf(2.0f * gg);               // tanh(g)
            float ch = (e2 - 1.0f) / (e2 + 1.0f);
            cv0 = cv0 * sg + ch * sg;
            float ca = fminf(fmaxf(cv0, -15.0f), 15.0f);
            float e3 = __expf(2.0f * ca);               // tanh(c)
            float th = (e3 - 1.0f) / (e3 + 1.0f);
            float hval = th * sg;
            hi = (int)(u32)__builtin_bit_cast(unsigned short, (_Float16)hval);
        }
        // pack rows (j0+c, j0+c+1) for c in {0,2}: neighbor lane holds +1
        int x1v = __shfl_down(hi, 1);
        if (c == 0 || c == 2) {
            const int w = s * 64 + g * 2 + (c >> 1);
            u32 pk = (u32)(unsigned short)hi | ((u32)(unsigned short)x1v << 16);
            u64 wv = (u64)pk | ((u64)(u32)(st + 1) << 32);
            st_llc(hx + ((size_t)((st + 1) & 1) * BATCH + b) * 256 + w, wv);
            h_lds[(st + 1) & 1][(w >> 4) * 20 + (w & 15)] = pk;  // local bypass
        }
        // no second barrier: next step's pollers write disjoint (remote) words,
        // and the next __syncthreads() orders these writes for the next dot.
    }
}

// -------------------------------------------------------------------------
// Kernel 3: output = h_final @ out_w.T + out_b. Final h in hx buffer 0
// (TOT_STEPS even), 2 fp16 in each word's low 32 bits.
// -------------------------------------------------------------------------
__global__ __launch_bounds__(256) void out_kernel(
    const u64* __restrict__ hx,
    const float* __restrict__ out_w,
    const float* __restrict__ out_b,
    float* __restrict__ out)
{
    const int b  = blockIdx.x;    // 64
    const int jt = threadIdx.x;   // 256
    __shared__ float hrow[512];

    {
        u64 v = hx[(size_t)b * 256 + jt];
        h2 pr = __builtin_bit_cast(h2, (u32)v);
        hrow[2 * jt]     = (float)pr.x;
        hrow[2 * jt + 1] = (float)pr.y;
    }
    __syncthreads();

    float acc = out_b[jt];
    const float* wr = out_w + (size_t)jt * HID;
    #pragma unroll 8
    for (int k = 0; k < HID; ++k)
        acc += hrow[k] * wr[k];
    out[(size_t)b * IN_SZ + jt] = acc;
}

// -------------------------------------------------------------------------
extern "C" void kernel_launch(void* const* d_in, const int* in_sizes, int n_in,
                              void* d_out, int out_size, void* d_ws, size_t ws_size,
                              hipStream_t stream)
{
    const float* input  = (const float*)d_in[0];
    const float* gate_w = (const float*)d_in[1];
    const float* gate_b = (const float*)d_in[2];
    const float* out_w  = (const float*)d_in[3];
    const float* out_b  = (const float*)d_in[4];
    float* out = (float*)d_out;

    // ws layout: Xproj fp32 (256 MB) | hx [2][64][256] u64 (256 KB)
    float* xproj = (float*)d_ws;
    const size_t xbytes = (size_t)T_STEPS * BATCH * HID * sizeof(float);
    u64* hx = (u64*)((char*)d_ws + xbytes);

    // zero the exchange every launch: tag 0 == initial h = 0; graph replays
    // must never see stale tags.
    (void)hipMemsetAsync(hx, 0, (size_t)2 * BATCH * 256 * sizeof(u64), stream);

    dim3 g1(8, 64);
    xproj_kernel<<<g1, 256, 0, stream>>>(input, gate_w, gate_b, xproj);
    lstm_kernel<<<256, 512, 0, stream>>>(gate_w, xproj, hx);
    out_kernel<<<64, 256, 0, stream>>>(hx, out_w, out_b, out);
}